// Round 4
// baseline (309.476 us; speedup 1.0000x reference)
//
#include <hip/hip_runtime.h>

// MoE forward: B=4 S=2048 D=768 E=8 K=2, T=8192 tokens.
// out = sum over top-2 experts w_e * (relu(x@W1[e]+b1[e]) @ W2[e] + b2[e]), plus aux loss scalar.

#define T_TOK 8192
#define D_DIM 768
#define E_EXP 8
#define TK    16384   // T*K rows total across expert groups

typedef __attribute__((ext_vector_type(4))) float f32x4;
typedef __attribute__((ext_vector_type(8))) short s16x8;
typedef __attribute__((ext_vector_type(8))) unsigned short u16x8;

static __device__ __forceinline__ unsigned short f2bf(float f) {
    union { float f; unsigned u; } v; v.f = f;
    unsigned r = v.u + 0x7FFFu + ((v.u >> 16) & 1u);   // RNE
    return (unsigned short)(r >> 16);
}
static __device__ __forceinline__ float bf2f(unsigned short h) {
    union { unsigned u; float f; } v; v.u = ((unsigned)h) << 16;
    return v.f;
}

// async global->LDS, 16B per lane; LDS dest is wave-uniform base + lane*16
static __device__ __forceinline__ void gload_lds16(const unsigned short* g, unsigned short* l) {
    __builtin_amdgcn_global_load_lds(
        (const __attribute__((address_space(1))) unsigned int*)(const void*)g,
        (__attribute__((address_space(3))) unsigned int*)(void*)l,
        16, 0, 0);
}

// ---------------- gate: logits, softmax, top-2, x->bf16, counts/importance, last-block prefix+aux ----------------
__global__ __launch_bounds__(256) void gate_kernel(
    const float* __restrict__ x, const float* __restrict__ gw,
    const float* __restrict__ gb, unsigned short* __restrict__ xb,
    int* __restrict__ ea, int* __restrict__ eb,
    float* __restrict__ wa, float* __restrict__ wb,
    int* __restrict__ counts, float* __restrict__ importance,
    int* __restrict__ basep, int* __restrict__ cursor,
    int* __restrict__ done, float* __restrict__ aux_out)
{
    __shared__ float s_imp[4][8];
    __shared__ int   s_cnt[4][8];
    const int tid = threadIdx.x, wid = tid >> 6, lane = tid & 63;
    const int wg = blockIdx.x * 4 + wid;      // 1024 waves total

    float imp[8]; int cnt[8];
    #pragma unroll
    for (int e = 0; e < 8; ++e) { imp[e] = 0.f; cnt[e] = 0; }

    for (int i = 0; i < 8; ++i) {
        const int t = wg + i * 1024;
        const float* xr = x + (size_t)t * D_DIM;
        float xv[12];
        float acc[8];
        #pragma unroll
        for (int e = 0; e < 8; ++e) acc[e] = 0.f;
        #pragma unroll
        for (int j = 0; j < 12; ++j) {
            const int d = lane + j * 64;
            float v = xr[d];
            xv[j] = v;
            xb[(size_t)t * D_DIM + d] = f2bf(v);
        }
        #pragma unroll
        for (int j = 0; j < 12; ++j) {
            const int d = lane + j * 64;
            const f32x4* g = (const f32x4*)(gw + (size_t)d * 8);
            f32x4 g0 = g[0], g1 = g[1];
            float v = xv[j];
            acc[0] += v * g0[0]; acc[1] += v * g0[1];
            acc[2] += v * g0[2]; acc[3] += v * g0[3];
            acc[4] += v * g1[0]; acc[5] += v * g1[1];
            acc[6] += v * g1[2]; acc[7] += v * g1[3];
        }
        #pragma unroll
        for (int s = 1; s < 64; s <<= 1) {
            #pragma unroll
            for (int e = 0; e < 8; ++e) acc[e] += __shfl_xor(acc[e], s);
        }
        float lg[8], mx = -1e30f;
        #pragma unroll
        for (int e = 0; e < 8; ++e) { lg[e] = acc[e] + gb[e]; mx = fmaxf(mx, lg[e]); }
        float p[8], ssum = 0.f;
        #pragma unroll
        for (int e = 0; e < 8; ++e) { p[e] = expf(lg[e] - mx); ssum += p[e]; }
        float sc[8];
        float inv_s = 1.f / ssum;
        #pragma unroll
        for (int e = 0; e < 8; ++e) { sc[e] = p[e] * inv_s; imp[e] += sc[e]; }
        // top-2 via scalar tracking (rule #20: no runtime-indexed register arrays).
        // Strict > with ascending e == first-index-wins ties, matching lax.top_k.
        float v0 = sc[0], v1 = -1e30f;
        int   i0 = 0,     i1 = -1;
        #pragma unroll
        for (int e = 1; e < 8; ++e) {
            if (sc[e] > v0)      { v1 = v0; i1 = i0; v0 = sc[e]; i0 = e; }
            else if (sc[e] > v1) { v1 = sc[e]; i1 = e; }
        }
        #pragma unroll
        for (int e = 0; e < 8; ++e) cnt[e] += (e == i0 ? 1 : 0) + (e == i1 ? 1 : 0);
        float inv = 1.f / (v0 + v1 + 1e-8f);
        if (lane == 0) {
            ea[t] = i0; eb[t] = i1; wa[t] = v0 * inv; wb[t] = v1 * inv;
        }
    }
    if (lane == 0) {
        #pragma unroll
        for (int e = 0; e < 8; ++e) { s_imp[wid][e] = imp[e]; s_cnt[wid][e] = cnt[e]; }
    }
    __syncthreads();
    if (tid < 8) {
        float si = 0.f; int sc2 = 0;
        #pragma unroll
        for (int w = 0; w < 4; ++w) { si += s_imp[w][tid]; sc2 += s_cnt[w][tid]; }
        atomicAdd(importance + tid, si);
        atomicAdd(counts + tid, sc2);
    }
    // last finishing block computes prefix bases + aux loss (device-scope)
    __threadfence();
    __syncthreads();
    if (tid == 0) {
        if (atomicAdd(done, 1) == (int)gridDim.x - 1) {
            int c[8]; float im[8];
            #pragma unroll
            for (int e = 0; e < 8; ++e) {
                c[e]  = atomicAdd(counts + e, 0);        // device-scope read
                im[e] = atomicAdd(importance + e, 0.0f);
            }
            int b = 0;
            #pragma unroll
            for (int e = 0; e < 8; ++e) { basep[e] = b; cursor[e] = b; b += c[e]; }
            float mean = 0.f;
            #pragma unroll
            for (int e = 0; e < 8; ++e) mean += im[e];
            mean *= 0.125f;
            float var = 0.f;
            #pragma unroll
            for (int e = 0; e < 8; ++e) { float d = im[e] - mean; var += d * d; }
            var *= 0.125f;
            aux_out[0] = 0.01f * var / (mean * mean + 1e-8f);
        }
    }
}

// ---------------- wave-aggregated scatter into per-expert lists ----------------
__global__ __launch_bounds__(256) void scatter_kernel(
    const int* __restrict__ ea, const int* __restrict__ eb,
    const float* __restrict__ wa, const float* __restrict__ wb,
    int* __restrict__ cursor, int* __restrict__ list,
    float* __restrict__ wgt, int* __restrict__ slot)
{
    const int t = blockIdx.x * 256 + threadIdx.x;
    const int lane = threadIdx.x & 63;
    #pragma unroll
    for (int k = 0; k < 2; ++k) {
        const int e = k ? eb[t] : ea[t];
        const float w = k ? wb[t] : wa[t];
        int pos = 0;
        for (int ex = 0; ex < 8; ++ex) {
            unsigned long long m = __ballot(e == ex);
            if (e == ex) {
                int leader = __ffsll((unsigned long long)m) - 1;
                int n = __popcll(m);
                int p0 = 0;
                if (lane == leader) p0 = atomicAdd(cursor + ex, n);
                p0 = __shfl(p0, leader);
                pos = p0 + __popcll(m & ((1ull << lane) - 1ull));
            }
        }
        list[pos] = t; wgt[pos] = w; slot[t * 2 + k] = pos;
    }
}

// ---------------- transpose+convert weights: [e][k][n] f32 -> [e][n][k] bf16 ----------------
__global__ __launch_bounds__(256) void tconv_kernel(
    const float* __restrict__ w1, const float* __restrict__ w2,
    unsigned short* __restrict__ w1t, unsigned short* __restrict__ w2t)
{
    const int z = blockIdx.z;
    const float* src = (z < 8 ? w1 : w2) + (size_t)(z & 7) * D_DIM * D_DIM;
    unsigned short* dst = (z < 8 ? w1t : w2t) + (size_t)(z & 7) * D_DIM * D_DIM;
    __shared__ float tile[32][33];
    const int tx = threadIdx.x, ty = threadIdx.y;
    const int k0 = blockIdx.x * 32, n0 = blockIdx.y * 32;
    #pragma unroll
    for (int j = 0; j < 4; ++j)
        tile[ty + j * 8][tx] = src[(size_t)(k0 + ty + j * 8) * D_DIM + n0 + tx];
    __syncthreads();
    #pragma unroll
    for (int j = 0; j < 4; ++j)
        dst[(size_t)(n0 + ty + j * 8) * D_DIM + k0 + tx] = f2bf(tile[tx][ty + j * 8]);
}

// ---------------- grouped GEMM: 3-buffer 2-deep counted-vmcnt pipeline ----------------
// C[m][n] = act(A[m][:] @ W[:,n] + bias[n]); A rows gathered via list (GATHER=1) or contiguous.
// Bt is [e][n][k] bf16. 128x128 tile, 4 waves, BK=32, mfma_f32_16x16x32_bf16.
// Per iter t: issue stage(t+2) -> ds_read+MFMA on tile t -> s_waitcnt vmcnt(4) (tile t+1 ready,
// tile t+2 stays in flight across the barrier) -> s_barrier. Invariant: 4 loads/wave outstanding
// at loop entry. Last two iters drain with vmcnt(0).
template<int GATHER, int RELU>
__global__ __launch_bounds__(256) void moe_gemm_kernel(
    const unsigned short* __restrict__ A, const unsigned short* __restrict__ Bt,
    const float* __restrict__ bias, unsigned short* __restrict__ C,
    const int* __restrict__ counts, const int* __restrict__ basep,
    const int* __restrict__ list)
{
    const int e = blockIdx.z;
    const int count = counts[e];
    const int m0 = blockIdx.x * 128;
    if (m0 >= count) return;
    const int n0 = blockIdx.y * 128;
    const int base = basep[e];

    constexpr int NT = D_DIM / 32;   // 24 K-tiles
    constexpr int LB = 128 * 32;     // elems per LDS buffer

    __shared__ unsigned short Al[3 * LB];
    __shared__ unsigned short Bl[3 * LB];

    const int tid = threadIdx.x;
    const int lane = tid & 63, wid = tid >> 6;
    const int wr = wid >> 1, wc = wid & 1;

    // staging map: wave wid covers rows wid*16..+15 (pass0) and +64 (pass1); lane->row/col
    const int sr = wid * 16 + (lane >> 2);   // 0..63
    const int sc = (lane & 3) * 8;           // k elems (16B)

    int r0 = m0 + sr;      if (r0 >= count) r0 = count - 1;
    int r1 = m0 + 64 + sr; if (r1 >= count) r1 = count - 1;
    const size_t t0 = GATHER ? (size_t)list[base + r0] : (size_t)(base + r0);
    const size_t t1 = GATHER ? (size_t)list[base + r1] : (size_t)(base + r1);
    const unsigned short* gA0 = A + t0 * D_DIM + sc;
    const unsigned short* gA1 = A + t1 * D_DIM + sc;
    const unsigned short* gB0 = Bt + ((size_t)e * D_DIM + n0 + sr) * D_DIM + sc;
    const unsigned short* gB1 = Bt + ((size_t)e * D_DIM + n0 + 64 + sr) * D_DIM + sc;
    const int lds0 = (wid * 16) * 32;        // wave-uniform LDS elem offsets
    const int lds1 = (64 + wid * 16) * 32;

    f32x4 acc[4][4];
    #pragma unroll
    for (int mi = 0; mi < 4; ++mi)
        #pragma unroll
        for (int ni = 0; ni < 4; ++ni)
            acc[mi][ni] = (f32x4)(0.f);

#define STAGE(kt, bi) do {                                   \
        const int _k = (kt) * 32;                            \
        gload_lds16(gA0 + _k, Al + (bi) * LB + lds0);        \
        gload_lds16(gA1 + _k, Al + (bi) * LB + lds1);        \
        gload_lds16(gB0 + _k, Bl + (bi) * LB + lds0);        \
        gload_lds16(gB1 + _k, Bl + (bi) * LB + lds1);        \
    } while (0)

    // prologue: tiles 0,1 in flight; wait tile 0 (newest 4 = tile 1 stay outstanding)
    STAGE(0, 0);
    STAGE(1, 1);
    asm volatile("s_waitcnt vmcnt(4)" ::: "memory");
    __builtin_amdgcn_s_barrier();
    __builtin_amdgcn_sched_barrier(0);

    #pragma unroll
    for (int t = 0; t < NT; ++t) {
        const int cb = t % 3;             // compute buffer (compile-time after unroll)
        const int sb = (t + 2) % 3;       // stage buffer
        if (t + 2 < NT) STAGE(t + 2, sb);

        s16x8 af[4], bfr[4];
        #pragma unroll
        for (int mi = 0; mi < 4; ++mi)
            af[mi] = *(const s16x8*)&Al[cb * LB + (wr * 64 + mi * 16 + (lane & 15)) * 32 + (lane >> 4) * 8];
        #pragma unroll
        for (int ni = 0; ni < 4; ++ni)
            bfr[ni] = *(const s16x8*)&Bl[cb * LB + (wc * 64 + ni * 16 + (lane & 15)) * 32 + (lane >> 4) * 8];
        #pragma unroll
        for (int mi = 0; mi < 4; ++mi)
            #pragma unroll
            for (int ni = 0; ni < 4; ++ni)
                acc[mi][ni] = __builtin_amdgcn_mfma_f32_16x16x32_bf16(
                    af[mi], bfr[ni], acc[mi][ni], 0, 0, 0);

        __builtin_amdgcn_sched_barrier(0);
        if (t + 2 < NT) { asm volatile("s_waitcnt vmcnt(4)" ::: "memory"); }
        else            { asm volatile("s_waitcnt vmcnt(0)" ::: "memory"); }
        __builtin_amdgcn_s_barrier();
        __builtin_amdgcn_sched_barrier(0);
    }
#undef STAGE

    // epilogue: C/D layout col=lane&15, row=(lane>>4)*4+j (verified m89)
    #pragma unroll
    for (int ni = 0; ni < 4; ++ni) {
        const int cn = n0 + wc * 64 + ni * 16 + (lane & 15);
        const float bv = bias[e * D_DIM + cn];
        #pragma unroll
        for (int mi = 0; mi < 4; ++mi) {
            #pragma unroll
            for (int j = 0; j < 4; ++j) {
                const int rm = m0 + wr * 64 + mi * 16 + (lane >> 4) * 4 + j;
                if (rm < count) {
                    float v = acc[mi][ni][j] + bv;
                    if (RELU) v = fmaxf(v, 0.f);
                    C[(size_t)(base + rm) * D_DIM + cn] = f2bf(v);
                }
            }
        }
    }
}

// ---------------- combine: out[t] = w0*y[slot0] + w1*y[slot1] ----------------
__global__ __launch_bounds__(256) void combine_kernel(
    const unsigned short* __restrict__ y, const int* __restrict__ slot,
    const float* __restrict__ wgt, float* __restrict__ out)
{
    const int g = blockIdx.x * 256 + threadIdx.x;   // 8-elem chunk id
    const int t = g / 96;                           // 96 chunks per 768-row
    const int n = (g % 96) * 8;
    const int s0 = slot[t * 2], s1 = slot[t * 2 + 1];
    const float w0 = wgt[s0], w1 = wgt[s1];
    u16x8 ya = *(const u16x8*)(y + (size_t)s0 * D_DIM + n);
    u16x8 yb = *(const u16x8*)(y + (size_t)s1 * D_DIM + n);
    f32x4 o0, o1;
    #pragma unroll
    for (int i = 0; i < 4; ++i) o0[i] = w0 * bf2f(ya[i])     + w1 * bf2f(yb[i]);
    #pragma unroll
    for (int i = 0; i < 4; ++i) o1[i] = w0 * bf2f(ya[4 + i]) + w1 * bf2f(yb[4 + i]);
    float* op = out + (size_t)t * D_DIM + n;
    *(f32x4*)op       = o0;
    *(f32x4*)(op + 4) = o1;
}

extern "C" void kernel_launch(void* const* d_in, const int* in_sizes, int n_in,
                              void* d_out, int out_size, void* d_ws, size_t ws_size,
                              hipStream_t stream)
{
    const float* x  = (const float*)d_in[0];
    const float* gw = (const float*)d_in[1];
    const float* gb = (const float*)d_in[2];
    const float* w1 = (const float*)d_in[3];
    const float* b1 = (const float*)d_in[4];
    const float* w2 = (const float*)d_in[5];
    const float* b2 = (const float*)d_in[6];
    float* out = (float*)d_out;

    char* ws = (char*)d_ws;
    size_t off = 0;
    auto alloc = [&](size_t bytes) {
        char* p = ws + off; off += (bytes + 255) & ~(size_t)255; return p;
    };
    unsigned short* xb  = (unsigned short*)alloc((size_t)T_TOK * D_DIM * 2);
    unsigned short* w1t = (unsigned short*)alloc((size_t)E_EXP * D_DIM * D_DIM * 2);
    unsigned short* w2t = (unsigned short*)alloc((size_t)E_EXP * D_DIM * D_DIM * 2);
    unsigned short* h   = (unsigned short*)alloc((size_t)TK * D_DIM * 2);
    unsigned short* y   = (unsigned short*)alloc((size_t)TK * D_DIM * 2);
    int*   list = (int*)alloc(TK * 4);
    float* wgt  = (float*)alloc(TK * 4);
    int*   slot = (int*)alloc(TK * 4);
    int*   ea   = (int*)alloc(T_TOK * 4);
    int*   eb   = (int*)alloc(T_TOK * 4);
    float* wa   = (float*)alloc(T_TOK * 4);
    float* wb   = (float*)alloc(T_TOK * 4);
    int*   meta = (int*)alloc(256);
    int*   counts = meta;            // [8]
    int*   basep  = meta + 8;        // [8]
    int*   cursor = meta + 16;       // [8]
    int*   done   = meta + 24;       // [1]
    float* importance = (float*)(meta + 32);  // [8]

    hipMemsetAsync(meta, 0, 256, stream);
    tconv_kernel<<<dim3(24, 24, 16), dim3(32, 8), 0, stream>>>(w1, w2, w1t, w2t);
    gate_kernel<<<256, 256, 0, stream>>>(x, gw, gb, xb, ea, eb, wa, wb, counts, importance,
                                         basep, cursor, done, out + (out_size - 1));
    scatter_kernel<<<32, 256, 0, stream>>>(ea, eb, wa, wb, cursor, list, wgt, slot);
    moe_gemm_kernel<1, 1><<<dim3(64, 6, 8), 256, 0, stream>>>(xb, w1t, b1, h, counts, basep, list);
    moe_gemm_kernel<0, 0><<<dim3(64, 6, 8), 256, 0, stream>>>(h, w2t, b2, y, counts, basep, list);
    combine_kernel<<<3072, 256, 0, stream>>>(y, slot, wgt, out);
}

// Round 6
// 296.157 us; speedup vs baseline: 1.0450x; 1.0450x over previous
//
#include <hip/hip_runtime.h>

// MoE forward: B=4 S=2048 D=768 E=8 K=2, T=8192 tokens.
// out = sum over top-2 experts w_e * (relu(x@W1[e]+b1[e]) @ W2[e] + b2[e]), plus aux loss scalar.

#define T_TOK 8192
#define D_DIM 768
#define E_EXP 8
#define TK    16384   // T*K rows total across expert groups
#define MAXCHUNK 136  // >= max possible sum_e ceil(count_e/128) = 135

typedef __attribute__((ext_vector_type(4))) float f32x4;
typedef __attribute__((ext_vector_type(8))) short s16x8;
typedef __attribute__((ext_vector_type(8))) unsigned short u16x8;

static __device__ __forceinline__ unsigned short f2bf(float f) {
    union { float f; unsigned u; } v; v.f = f;
    unsigned r = v.u + 0x7FFFu + ((v.u >> 16) & 1u);   // RNE
    return (unsigned short)(r >> 16);
}
static __device__ __forceinline__ float bf2f(unsigned short h) {
    union { unsigned u; float f; } v; v.u = ((unsigned)h) << 16;
    return v.f;
}

// async global->LDS, 16B per lane; LDS dest is wave-uniform base + lane*16
static __device__ __forceinline__ void gload_lds16(const unsigned short* g, unsigned short* l) {
    __builtin_amdgcn_global_load_lds(
        (const __attribute__((address_space(1))) unsigned int*)(const void*)g,
        (__attribute__((address_space(3))) unsigned int*)(void*)l,
        16, 0, 0);
}

// ---------------- gate: logits, softmax, top-2, x->bf16, counts/importance, last-block prefix+aux+chunkmap ----------------
__global__ __launch_bounds__(256) void gate_kernel(
    const float* __restrict__ x, const float* __restrict__ gw,
    const float* __restrict__ gb, unsigned short* __restrict__ xb,
    int* __restrict__ ea, int* __restrict__ eb,
    float* __restrict__ wa, float* __restrict__ wb,
    int* __restrict__ counts, float* __restrict__ importance,
    int* __restrict__ basep, int* __restrict__ cursor,
    int* __restrict__ done, float* __restrict__ aux_out,
    int* __restrict__ nchunks, int* __restrict__ c2e, int* __restrict__ c2m)
{
    __shared__ float s_imp[4][8];
    __shared__ int   s_cnt[4][8];
    const int tid = threadIdx.x, wid = tid >> 6, lane = tid & 63;
    const int wg = blockIdx.x * 4 + wid;      // 1024 waves total

    float imp[8]; int cnt[8];
    #pragma unroll
    for (int e = 0; e < 8; ++e) { imp[e] = 0.f; cnt[e] = 0; }

    for (int i = 0; i < 8; ++i) {
        const int t = wg + i * 1024;
        const float* xr = x + (size_t)t * D_DIM;
        float xv[12];
        float acc[8];
        #pragma unroll
        for (int e = 0; e < 8; ++e) acc[e] = 0.f;
        #pragma unroll
        for (int j = 0; j < 12; ++j) {
            const int d = lane + j * 64;
            float v = xr[d];
            xv[j] = v;
            xb[(size_t)t * D_DIM + d] = f2bf(v);
        }
        #pragma unroll
        for (int j = 0; j < 12; ++j) {
            const int d = lane + j * 64;
            const f32x4* g = (const f32x4*)(gw + (size_t)d * 8);
            f32x4 g0 = g[0], g1 = g[1];
            float v = xv[j];
            acc[0] += v * g0[0]; acc[1] += v * g0[1];
            acc[2] += v * g0[2]; acc[3] += v * g0[3];
            acc[4] += v * g1[0]; acc[5] += v * g1[1];
            acc[6] += v * g1[2]; acc[7] += v * g1[3];
        }
        #pragma unroll
        for (int s = 1; s < 64; s <<= 1) {
            #pragma unroll
            for (int e = 0; e < 8; ++e) acc[e] += __shfl_xor(acc[e], s);
        }
        float lg[8], mx = -1e30f;
        #pragma unroll
        for (int e = 0; e < 8; ++e) { lg[e] = acc[e] + gb[e]; mx = fmaxf(mx, lg[e]); }
        float p[8], ssum = 0.f;
        #pragma unroll
        for (int e = 0; e < 8; ++e) { p[e] = expf(lg[e] - mx); ssum += p[e]; }
        float sc[8];
        float inv_s = 1.f / ssum;
        #pragma unroll
        for (int e = 0; e < 8; ++e) { sc[e] = p[e] * inv_s; imp[e] += sc[e]; }
        // top-2 via scalar tracking (rule #20: no runtime-indexed register arrays).
        // Strict > with ascending e == first-index-wins ties, matching lax.top_k.
        float v0 = sc[0], v1 = -1e30f;
        int   i0 = 0,     i1 = -1;
        #pragma unroll
        for (int e = 1; e < 8; ++e) {
            if (sc[e] > v0)      { v1 = v0; i1 = i0; v0 = sc[e]; i0 = e; }
            else if (sc[e] > v1) { v1 = sc[e]; i1 = e; }
        }
        #pragma unroll
        for (int e = 0; e < 8; ++e) cnt[e] += (e == i0 ? 1 : 0) + (e == i1 ? 1 : 0);
        float inv = 1.f / (v0 + v1 + 1e-8f);
        if (lane == 0) {
            ea[t] = i0; eb[t] = i1; wa[t] = v0 * inv; wb[t] = v1 * inv;
        }
    }
    if (lane == 0) {
        #pragma unroll
        for (int e = 0; e < 8; ++e) { s_imp[wid][e] = imp[e]; s_cnt[wid][e] = cnt[e]; }
    }
    __syncthreads();
    if (tid < 8) {
        float si = 0.f; int sc2 = 0;
        #pragma unroll
        for (int w = 0; w < 4; ++w) { si += s_imp[w][tid]; sc2 += s_cnt[w][tid]; }
        atomicAdd(importance + tid, si);
        atomicAdd(counts + tid, sc2);
    }
    // last finishing block computes prefix bases + chunk map + aux loss (device-scope)
    __threadfence();
    __syncthreads();
    if (tid == 0) {
        if (atomicAdd(done, 1) == (int)gridDim.x - 1) {
            int c[8]; float im[8];
            #pragma unroll
            for (int e = 0; e < 8; ++e) {
                c[e]  = atomicAdd(counts + e, 0);        // device-scope read
                im[e] = atomicAdd(importance + e, 0.0f);
            }
            int b = 0, nc = 0;
            #pragma unroll
            for (int e = 0; e < 8; ++e) {
                basep[e] = b; cursor[e] = b;
                for (int m = 0; m < c[e]; m += 128) { c2e[nc] = e; c2m[nc] = m; ++nc; }
                b += c[e];
            }
            nchunks[0] = nc;
            float mean = 0.f;
            #pragma unroll
            for (int e = 0; e < 8; ++e) mean += im[e];
            mean *= 0.125f;
            float var = 0.f;
            #pragma unroll
            for (int e = 0; e < 8; ++e) { float d = im[e] - mean; var += d * d; }
            var *= 0.125f;
            aux_out[0] = 0.01f * var / (mean * mean + 1e-8f);
        }
    }
}

// ---------------- wave-aggregated scatter into per-expert lists ----------------
__global__ __launch_bounds__(256) void scatter_kernel(
    const int* __restrict__ ea, const int* __restrict__ eb,
    const float* __restrict__ wa, const float* __restrict__ wb,
    int* __restrict__ cursor, int* __restrict__ list,
    float* __restrict__ wgt, int* __restrict__ slot)
{
    const int t = blockIdx.x * 256 + threadIdx.x;
    const int lane = threadIdx.x & 63;
    #pragma unroll
    for (int k = 0; k < 2; ++k) {
        const int e = k ? eb[t] : ea[t];
        const float w = k ? wb[t] : wa[t];
        int pos = 0;
        for (int ex = 0; ex < 8; ++ex) {
            unsigned long long m = __ballot(e == ex);
            if (e == ex) {
                int leader = __ffsll((unsigned long long)m) - 1;
                int n = __popcll(m);
                int p0 = 0;
                if (lane == leader) p0 = atomicAdd(cursor + ex, n);
                p0 = __shfl(p0, leader);
                pos = p0 + __popcll(m & ((1ull << lane) - 1ull));
            }
        }
        list[pos] = t; wgt[pos] = w; slot[t * 2 + k] = pos;
    }
}

// ---------------- transpose+convert weights: [e][k][n] f32 -> [e][n][k] bf16 ----------------
__global__ __launch_bounds__(256) void tconv_kernel(
    const float* __restrict__ w1, const float* __restrict__ w2,
    unsigned short* __restrict__ w1t, unsigned short* __restrict__ w2t)
{
    const int z = blockIdx.z;
    const float* src = (z < 8 ? w1 : w2) + (size_t)(z & 7) * D_DIM * D_DIM;
    unsigned short* dst = (z < 8 ? w1t : w2t) + (size_t)(z & 7) * D_DIM * D_DIM;
    __shared__ float tile[32][33];
    const int tx = threadIdx.x, ty = threadIdx.y;
    const int k0 = blockIdx.x * 32, n0 = blockIdx.y * 32;
    #pragma unroll
    for (int j = 0; j < 4; ++j)
        tile[ty + j * 8][tx] = src[(size_t)(k0 + ty + j * 8) * D_DIM + n0 + tx];
    __syncthreads();
    #pragma unroll
    for (int j = 0; j < 4; ++j)
        dst[(size_t)(n0 + ty + j * 8) * D_DIM + k0 + tx] = f2bf(tile[tx][ty + j * 8]);
}

// ---------------- grouped GEMM: dense chunk-map grid, 3-buffer 2-deep counted-vmcnt pipeline ----------------
// C[m][n] = act(A[m][:] @ W[:,n] + bias[n]); A rows gathered via list (GATHER=1) or contiguous.
// Bt is [e][n][k] bf16. 128x128 tile, 4 waves, BK=32, mfma_f32_16x16x32_bf16.
// Grid x = chunk id (dense over experts' M-blocks, built by gate's last block), y = N-chunk.
template<int GATHER, int RELU>
__global__ __launch_bounds__(256) void moe_gemm_kernel(
    const unsigned short* __restrict__ A, const unsigned short* __restrict__ Bt,
    const float* __restrict__ bias, unsigned short* __restrict__ C,
    const int* __restrict__ counts, const int* __restrict__ basep,
    const int* __restrict__ list,
    const int* __restrict__ nchunks, const int* __restrict__ c2e,
    const int* __restrict__ c2m)
{
    const int cid = blockIdx.x;
    if (cid >= nchunks[0]) return;
    const int e = c2e[cid];
    const int m0 = c2m[cid];
    const int count = counts[e];
    const int n0 = blockIdx.y * 128;
    const int base = basep[e];

    constexpr int NT = D_DIM / 32;   // 24 K-tiles
    constexpr int LB = 128 * 32;     // elems per LDS buffer

    __shared__ unsigned short Al[3 * LB];
    __shared__ unsigned short Bl[3 * LB];

    const int tid = threadIdx.x;
    const int lane = tid & 63, wid = tid >> 6;
    const int wr = wid >> 1, wc = wid & 1;

    // staging map: wave wid covers rows wid*16..+15 (pass0) and +64 (pass1); lane->row/col
    const int sr = wid * 16 + (lane >> 2);   // 0..63
    const int sc = (lane & 3) * 8;           // k elems (16B)

    int r0 = m0 + sr;      if (r0 >= count) r0 = count - 1;
    int r1 = m0 + 64 + sr; if (r1 >= count) r1 = count - 1;
    const size_t t0 = GATHER ? (size_t)list[base + r0] : (size_t)(base + r0);
    const size_t t1 = GATHER ? (size_t)list[base + r1] : (size_t)(base + r1);
    const unsigned short* gA0 = A + t0 * D_DIM + sc;
    const unsigned short* gA1 = A + t1 * D_DIM + sc;
    const unsigned short* gB0 = Bt + ((size_t)e * D_DIM + n0 + sr) * D_DIM + sc;
    const unsigned short* gB1 = Bt + ((size_t)e * D_DIM + n0 + 64 + sr) * D_DIM + sc;
    const int lds0 = (wid * 16) * 32;        // wave-uniform LDS elem offsets
    const int lds1 = (64 + wid * 16) * 32;

    f32x4 acc[4][4];
    #pragma unroll
    for (int mi = 0; mi < 4; ++mi)
        #pragma unroll
        for (int ni = 0; ni < 4; ++ni)
            acc[mi][ni] = (f32x4)(0.f);

#define STAGE(kt, bi) do {                                   \
        const int _k = (kt) * 32;                            \
        gload_lds16(gA0 + _k, Al + (bi) * LB + lds0);        \
        gload_lds16(gA1 + _k, Al + (bi) * LB + lds1);        \
        gload_lds16(gB0 + _k, Bl + (bi) * LB + lds0);        \
        gload_lds16(gB1 + _k, Bl + (bi) * LB + lds1);        \
    } while (0)

    // prologue: tiles 0,1 in flight; wait tile 0 (newest 4 = tile 1 stay outstanding)
    STAGE(0, 0);
    STAGE(1, 1);
    asm volatile("s_waitcnt vmcnt(4)" ::: "memory");
    __builtin_amdgcn_s_barrier();
    __builtin_amdgcn_sched_barrier(0);

    #pragma unroll
    for (int t = 0; t < NT; ++t) {
        const int cb = t % 3;             // compute buffer (compile-time after unroll)
        const int sb = (t + 2) % 3;       // stage buffer
        if (t + 2 < NT) STAGE(t + 2, sb);

        s16x8 af[4], bfr[4];
        #pragma unroll
        for (int mi = 0; mi < 4; ++mi)
            af[mi] = *(const s16x8*)&Al[cb * LB + (wr * 64 + mi * 16 + (lane & 15)) * 32 + (lane >> 4) * 8];
        #pragma unroll
        for (int ni = 0; ni < 4; ++ni)
            bfr[ni] = *(const s16x8*)&Bl[cb * LB + (wc * 64 + ni * 16 + (lane & 15)) * 32 + (lane >> 4) * 8];
        #pragma unroll
        for (int mi = 0; mi < 4; ++mi)
            #pragma unroll
            for (int ni = 0; ni < 4; ++ni)
                acc[mi][ni] = __builtin_amdgcn_mfma_f32_16x16x32_bf16(
                    af[mi], bfr[ni], acc[mi][ni], 0, 0, 0);

        __builtin_amdgcn_sched_barrier(0);
        if (t + 2 < NT) { asm volatile("s_waitcnt vmcnt(4)" ::: "memory"); }
        else            { asm volatile("s_waitcnt vmcnt(0)" ::: "memory"); }
        __builtin_amdgcn_s_barrier();
        __builtin_amdgcn_sched_barrier(0);
    }
#undef STAGE

    // epilogue: C/D layout col=lane&15, row=(lane>>4)*4+j (verified m89)
    #pragma unroll
    for (int ni = 0; ni < 4; ++ni) {
        const int cn = n0 + wc * 64 + ni * 16 + (lane & 15);
        const float bv = bias[e * D_DIM + cn];
        #pragma unroll
        for (int mi = 0; mi < 4; ++mi) {
            #pragma unroll
            for (int j = 0; j < 4; ++j) {
                const int rm = m0 + wr * 64 + mi * 16 + (lane >> 4) * 4 + j;
                if (rm < count) {
                    float v = acc[mi][ni][j] + bv;
                    if (RELU) v = fmaxf(v, 0.f);
                    C[(size_t)(base + rm) * D_DIM + cn] = f2bf(v);
                }
            }
        }
    }
}

// ---------------- combine: out[t] = w0*y[slot0] + w1*y[slot1] ----------------
__global__ __launch_bounds__(256) void combine_kernel(
    const unsigned short* __restrict__ y, const int* __restrict__ slot,
    const float* __restrict__ wgt, float* __restrict__ out)
{
    const int g = blockIdx.x * 256 + threadIdx.x;   // 8-elem chunk id
    const int t = g / 96;                           // 96 chunks per 768-row
    const int n = (g % 96) * 8;
    const int s0 = slot[t * 2], s1 = slot[t * 2 + 1];
    const float w0 = wgt[s0], w1 = wgt[s1];
    u16x8 ya = *(const u16x8*)(y + (size_t)s0 * D_DIM + n);
    u16x8 yb = *(const u16x8*)(y + (size_t)s1 * D_DIM + n);
    f32x4 o0, o1;
    #pragma unroll
    for (int i = 0; i < 4; ++i) o0[i] = w0 * bf2f(ya[i])     + w1 * bf2f(yb[i]);
    #pragma unroll
    for (int i = 0; i < 4; ++i) o1[i] = w0 * bf2f(ya[4 + i]) + w1 * bf2f(yb[4 + i]);
    float* op = out + (size_t)t * D_DIM + n;
    *(f32x4*)op       = o0;
    *(f32x4*)(op + 4) = o1;
}

extern "C" void kernel_launch(void* const* d_in, const int* in_sizes, int n_in,
                              void* d_out, int out_size, void* d_ws, size_t ws_size,
                              hipStream_t stream)
{
    const float* x  = (const float*)d_in[0];
    const float* gw = (const float*)d_in[1];
    const float* gb = (const float*)d_in[2];
    const float* w1 = (const float*)d_in[3];
    const float* b1 = (const float*)d_in[4];
    const float* w2 = (const float*)d_in[5];
    const float* b2 = (const float*)d_in[6];
    float* out = (float*)d_out;

    char* ws = (char*)d_ws;
    size_t off = 0;
    auto alloc = [&](size_t bytes) {
        char* p = ws + off; off += (bytes + 255) & ~(size_t)255; return p;
    };
    unsigned short* xb  = (unsigned short*)alloc((size_t)T_TOK * D_DIM * 2);
    unsigned short* w1t = (unsigned short*)alloc((size_t)E_EXP * D_DIM * D_DIM * 2);
    unsigned short* w2t = (unsigned short*)alloc((size_t)E_EXP * D_DIM * D_DIM * 2);
    unsigned short* h   = (unsigned short*)alloc((size_t)TK * D_DIM * 2);
    unsigned short* y   = (unsigned short*)alloc((size_t)TK * D_DIM * 2);
    int*   list = (int*)alloc(TK * 4);
    float* wgt  = (float*)alloc(TK * 4);
    int*   slot = (int*)alloc(TK * 4);
    int*   ea   = (int*)alloc(T_TOK * 4);
    int*   eb   = (int*)alloc(T_TOK * 4);
    float* wa   = (float*)alloc(T_TOK * 4);
    float* wb   = (float*)alloc(T_TOK * 4);
    int*   meta = (int*)alloc(2048);
    int*   counts  = meta;            // [8]
    int*   basep   = meta + 8;        // [8]
    int*   cursor  = meta + 16;       // [8]
    int*   done    = meta + 24;       // [1]
    int*   nchunks = meta + 25;       // [1]
    float* importance = (float*)(meta + 26);  // [8]
    int*   c2e     = meta + 34;       // [MAXCHUNK]
    int*   c2m     = meta + 34 + MAXCHUNK;    // [MAXCHUNK]

    hipMemsetAsync(meta, 0, 2048, stream);
    tconv_kernel<<<dim3(24, 24, 16), dim3(32, 8), 0, stream>>>(w1, w2, w1t, w2t);
    gate_kernel<<<256, 256, 0, stream>>>(x, gw, gb, xb, ea, eb, wa, wb, counts, importance,
                                         basep, cursor, done, out + (out_size - 1),
                                         nchunks, c2e, c2m);
    scatter_kernel<<<32, 256, 0, stream>>>(ea, eb, wa, wb, cursor, list, wgt, slot);
    moe_gemm_kernel<1, 1><<<dim3(MAXCHUNK, 6), 256, 0, stream>>>(xb, w1t, b1, h, counts, basep, list,
                                                                 nchunks, c2e, c2m);
    moe_gemm_kernel<0, 0><<<dim3(MAXCHUNK, 6), 256, 0, stream>>>(h, w2t, b2, y, counts, basep, list,
                                                                 nchunks, c2e, c2m);
    combine_kernel<<<3072, 256, 0, stream>>>(y, slot, wgt, out);
}